// Round 10
// baseline (544.420 us; speedup 1.0000x reference)
//
#include <hip/hip_runtime.h>
#include <hip/hip_bf16.h>

typedef short short8v __attribute__((ext_vector_type(8)));
typedef float float4v __attribute__((ext_vector_type(4)));

constexpr int Bb = 64;    // batch
constexpr int Cc = 32;    // capsules (softmax axis)
constexpr int Nn = 1152;  // routes
constexpr int Oo = 64;    // out channels
constexpr int Ii = 64;    // in channels
constexpr int NCH = 32;   // n-chunks (grid.x)
constexpr int CHN = 36;   // n per chunk
constexpr int OT  = 8;    // o-tiles (grid.y), 8 o per block -> 2KB DRAM pieces

__device__ __forceinline__ unsigned short bf16_rne(float f) {
    unsigned u = __float_as_uint(f);
    u += 0x7FFFu + ((u >> 16) & 1u);
    return (unsigned short)(u >> 16);
}
__device__ __forceinline__ float bf16_f(unsigned short h) {
    return __uint_as_float(((unsigned)h) << 16);
}
__device__ __forceinline__ float squash_elem(float s) {
    float sq = s * s;
    return (sq / (1.f + sq)) * s / sqrtf(sq + 1e-8f);
}

// barrier WITHOUT vmcnt drain: DS ops complete (buffer safety) but global
// prefetch loads stay in flight across the barrier.
__device__ __forceinline__ void barrier_nodrain() {
    asm volatile("s_waitcnt lgkmcnt(0)" ::: "memory");
    __builtin_amdgcn_s_barrier();
    asm volatile("" ::: "memory");
}

// split 8 f32 (two float4) into hi/lo bf16 fragments (RNE both)
__device__ __forceinline__ void split8(const float4& f0, const float4& f1,
                                       short8v& h, short8v& lo) {
    float a[8] = {f0.x, f0.y, f0.z, f0.w, f1.x, f1.y, f1.z, f1.w};
#pragma unroll
    for (int e = 0; e < 8; ++e) {
        unsigned short hb = bf16_rne(a[e]);
        h[e] = (short)hb;
        lo[e] = (short)bf16_rne(a[e] - bf16_f(hb));
    }
}

// ---- pre-split + TRANSPOSE x -> xt[n][b][i] hi/lo bf16 planes --------------
__global__ __launch_bounds__(256) void prep_xt(const float* __restrict__ x,
                                               unsigned short* __restrict__ xh,
                                               unsigned short* __restrict__ xl) {
    const int n = blockIdx.x, t = threadIdx.x;
    const int b = t >> 2, q = t & 3;
    const float* src = x + ((size_t)b * Nn + n) * Ii + q * 16;
    float4 v0 = *(const float4*)(src);
    float4 v1 = *(const float4*)(src + 4);
    float4 v2 = *(const float4*)(src + 8);
    float4 v3 = *(const float4*)(src + 12);
    short8v h0, l0, h1, l1;
    split8(v0, v1, h0, l0);
    split8(v2, v3, h1, l1);
    size_t dst = (size_t)n * (Bb * Ii) + b * Ii + q * 16;
    *(short8v*)(xh + dst) = h0;
    *(short8v*)(xh + dst + 8) = h1;
    *(short8v*)(xl + dst) = l0;
    *(short8v*)(xl + dst + 8) = l1;
}

// ---- fused pass: recompute u via split-bf16 MFMA, route, partial-reduce ----
// MODE 0: acc += u (chained in MFMA C); MODE 1: acc += softmax_c(u*V) * u
// Block (n-chunk, o-oct): 512 thr / 8 waves; 64 b x 32 c x 8 o.
// Wave wv: bg = wv>>1 (16 b rows), q = wv&1 (o-quad). Per-wave shape = R9.
// DRAM pieces per (c,n) are 2KB contiguous; 1 block/CU; 1 barrier per n.
template <int MODE>
__global__ __launch_bounds__(512, 2) void caps_pass(
    const float* __restrict__ w, const unsigned short* __restrict__ xh,
    const unsigned short* __restrict__ xl, const float* __restrict__ V,
    float* __restrict__ part) {
    __shared__ unsigned short sh[2][256 * 64];  // hi plane (2 x 32 KB)
    __shared__ unsigned short sl[2][256 * 64];  // lo plane (2 x 32 KB)

    const int t = threadIdx.x;
    const int l = t & 63, wv = t >> 6;          // 8 waves
    const int bg = wv >> 1, q = wv & 1;
    const int ch = blockIdx.x, ot = blockIdx.y;
    const int obase = ot * 8;
    const int kg = l >> 4, lm = l & 15;
    const int cc = (l >> 2) & 3, ol3 = l & 3;
    const int o = obase + 4 * q + ol3;
    const int n0 = ch * CHN;

    // per-lane V: b = 16bg+4kg+r, c = 4t8+cc, o fixed
    float Vreg[8][4];
    if constexpr (MODE == 1) {
#pragma unroll
        for (int t8 = 0; t8 < 8; ++t8)
#pragma unroll
            for (int r = 0; r < 4; ++r)
                Vreg[t8][r] =
                    V[((size_t)(16 * bg + 4 * kg + r) * Cc + 4 * t8 + cc) * Oo + o];
    }
    float4v acc4[8];   // MODE 0 accumulators (chained through MFMA C)
    float accs[8][4];  // MODE 1 accumulators
#pragma unroll
    for (int t8 = 0; t8 < 8; ++t8) {
        acc4[t8] = (float4v){0.f, 0.f, 0.f, 0.f};
#pragma unroll
        for (int r = 0; r < 4; ++r) accs[t8][r] = 0.f;
    }

    // staging: thread covers 8 cols x 16B f32; col = (t>>4) + 32k, i0 = (t&15)*4
    // threads 0..127 cover one 2KB-contiguous (c,n) piece (8 o x 64 i).
    const int i0 = (t & 15) * 4;
    const int colb = t >> 4;     // 0..31
    float4 L[8];

    auto issue = [&](int n) {
#pragma unroll
        for (int k = 0; k < 8; ++k) {
            int col = colb + 32 * k;
            int c = col >> 3, olc = col & 7;
            L[k] = *(const float4*)(
                w + (((size_t)c * Nn + n) * Oo + obase + olc) * Ii + i0);
        }
    };
    auto writebuf = [&](unsigned short* dh, unsigned short* dl) {
#pragma unroll
        for (int k = 0; k < 8; ++k) {
            int col = colb + 32 * k;
            int key = (col & 3) | (((col >> 3) & 1) << 2);  // 3-bit slot key
            int off = col * 64 + (i0 ^ (key << 3));
            float a[4] = {L[k].x, L[k].y, L[k].z, L[k].w};
            ushort4 H, Lo;
            unsigned short* hp = (unsigned short*)&H;
            unsigned short* lp = (unsigned short*)&Lo;
#pragma unroll
            for (int e = 0; e < 4; ++e) {
                unsigned short hb = bf16_rne(a[e]);
                hp[e] = hb;
                lp[e] = bf16_rne(a[e] - bf16_f(hb));
            }
            *(ushort4*)(dh + off) = H;
            *(ushort4*)(dl + off) = Lo;
        }
    };

    auto compute = [&](const unsigned short* bh_, const unsigned short* bl_,
                       int n) {
        // A-frags from xt[n][b][i]: wave reads a contiguous 2KB region
        const size_t xoff =
            (size_t)n * (Bb * Ii) + (16 * bg + lm) * Ii + kg * 8;
        short8v ah0 = *(const short8v*)(xh + xoff);
        short8v al0 = *(const short8v*)(xl + xoff);
        short8v ah1 = *(const short8v*)(xh + xoff + 32);
        short8v al1 = *(const short8v*)(xl + xoff + 32);

        float u[8][4];
#pragma unroll
        for (int t8 = 0; t8 < 8; ++t8) {
            int col = 32 * t8 + 8 * cc + 4 * q + ol3;
            int key = ol3 | ((cc & 1) << 2);  // == (col&3)|(((col>>3)&1)<<2)
            int off0 = col * 64 + 8 * (kg ^ key);
            int off1 = col * 64 + 8 * ((kg + 4) ^ key);
            short8v bh0 = *(const short8v*)(bh_ + off0);
            short8v bl0 = *(const short8v*)(bl_ + off0);
            short8v bh1 = *(const short8v*)(bh_ + off1);
            short8v bl1 = *(const short8v*)(bl_ + off1);
            float4v a;
            if constexpr (MODE == 0) a = acc4[t8];
            else a = (float4v){0.f, 0.f, 0.f, 0.f};
            a = __builtin_amdgcn_mfma_f32_16x16x32_bf16(ah0, bh0, a, 0, 0, 0);
            a = __builtin_amdgcn_mfma_f32_16x16x32_bf16(al0, bh0, a, 0, 0, 0);
            a = __builtin_amdgcn_mfma_f32_16x16x32_bf16(ah0, bl0, a, 0, 0, 0);
            a = __builtin_amdgcn_mfma_f32_16x16x32_bf16(ah1, bh1, a, 0, 0, 0);
            a = __builtin_amdgcn_mfma_f32_16x16x32_bf16(al1, bh1, a, 0, 0, 0);
            a = __builtin_amdgcn_mfma_f32_16x16x32_bf16(ah1, bl1, a, 0, 0, 0);
            if constexpr (MODE == 0) {
                acc4[t8] = a;
            } else {
                u[t8][0] = a[0]; u[t8][1] = a[1];
                u[t8][2] = a[2]; u[t8][3] = a[3];
            }
        }
        if constexpr (MODE == 1) {
            // softmax over 32 c = 8 in-lane (t8) x 4 lanes (xor 4, 8)
#pragma unroll
            for (int r = 0; r < 4; ++r) {
                float m = -1e30f;
#pragma unroll
                for (int t8 = 0; t8 < 8; ++t8)
                    m = fmaxf(m, u[t8][r] * Vreg[t8][r]);
                m = fmaxf(m, __shfl_xor(m, 4));
                m = fmaxf(m, __shfl_xor(m, 8));
                float Z = 0.f;
#pragma unroll
                for (int t8 = 0; t8 < 8; ++t8) {
                    float e = __expf(u[t8][r] * Vreg[t8][r] - m);
                    Z += e;
                    u[t8][r] *= e;  // u now holds e*u
                }
                Z += __shfl_xor(Z, 4);
                Z += __shfl_xor(Z, 8);
                float rz = 1.f / Z;
#pragma unroll
                for (int t8 = 0; t8 < 8; ++t8) accs[t8][r] += u[t8][r] * rz;
            }
        }
    };

    // Single-L register pipeline: loads for n+1 issue right after L is
    // consumed into LDS; they land during compute(n). One barrier per n.
    issue(n0);
    for (int j = 0; j < CHN; ++j) {
        const int cur = j & 1;
        writebuf(sh[cur], sl[cur]);          // counted vmcnt wait on L
        if (j + 1 < CHN) issue(n0 + j + 1);  // refill L (anti-dep ordered)
        barrier_nodrain();                   // lgkm only; vmcnt stays in flight
        compute(sh[cur], sl[cur], n0 + j);
    }

    // write per-chunk partials: part[ch][b][c][o]
#pragma unroll
    for (int t8 = 0; t8 < 8; ++t8)
#pragma unroll
        for (int r = 0; r < 4; ++r) {
            int b = 16 * bg + 4 * kg + r;
            int c = 4 * t8 + cc;
            float val = (MODE == 0) ? acc4[t8][r] : accs[t8][r];
            part[(((size_t)ch * Bb + b) * Cc + c) * Oo + o] = val;
        }
}

// ---- reduce partials over chunks; squash; update V / write out -------------
__global__ void reduce_caps(const float* __restrict__ part,
                            float* __restrict__ V, float* __restrict__ out,
                            int mode) {
    int bc = blockIdx.x;       // b*32+c, 2048 blocks
    int o = threadIdx.x;       // 64
    size_t base = (size_t)bc * 64 + o;
    float s = 0.f;
    for (int c = 0; c < NCH; ++c) s += part[(size_t)c * (Bb * Cc * Oo) + base];
    if (mode == 0)      V[base] = squash_elem(s * (1.f / 32.f));
    else if (mode == 1) V[base] += squash_elem(s);
    else                out[base] = squash_elem(s);
}

extern "C" void kernel_launch(void* const* d_in, const int* in_sizes, int n_in,
                              void* d_out, int out_size, void* d_ws, size_t ws_size,
                              hipStream_t stream) {
    const float* x = (const float*)d_in[0];          // [64,1152,64]
    const float* w = (const float*)d_in[1];          // [32,1152,64,64]
    float* out = (float*)d_out;                      // [64,32,64]

    const size_t XE = (size_t)Bb * Nn * Ii;          // 4,718,592
    unsigned short* xh = (unsigned short*)d_ws;      // xt hi [n][b][i]
    unsigned short* xl = xh + XE;                    // xt lo
    float* part = (float*)(xl + XE);                 // 32*64*32*64 f32 ~ 17 MB
    float* V = part + (size_t)NCH * Bb * Cc * Oo;

    prep_xt<<<Nn, 256, 0, stream>>>(x, xh, xl);

    caps_pass<0><<<dim3(NCH, OT), 512, 0, stream>>>(w, xh, xl, nullptr, part);
    reduce_caps<<<Bb * Cc, 64, 0, stream>>>(part, V, out, 0);   // V = v0
    caps_pass<1><<<dim3(NCH, OT), 512, 0, stream>>>(w, xh, xl, V, part);
    reduce_caps<<<Bb * Cc, 64, 0, stream>>>(part, V, out, 1);   // V += v1
    caps_pass<1><<<dim3(NCH, OT), 512, 0, stream>>>(w, xh, xl, V, part);
    reduce_caps<<<Bb * Cc, 64, 0, stream>>>(part, V, out, 2);   // out = v2
}